// Round 11
// baseline (91.816 us; speedup 1.0000x reference)
//
#include <hip/hip_runtime.h>
#include <math.h>

#define NB 8
#define KC 64
#define S1C 5
#define CC 128
#define PP 1936
#define PT 64
#define NPT 31             /* ceil(1936/64) */
#define NTILE (NB * NPT)   /* 248 tiles */
#define NBLK (NTILE / 2)   /* 124 blocks, 2 tiles each (dispatch-ramp cut) */
#define ALPHAF 1500.0f
#define EPSF 1e-12f

/* ws layout (floats): part[248][64][128] ; ps[248][64]  (~8.2 MB) */
#define WS_PART  ((size_t)NTILE * KC * CC)
#define WS_MAIN_FLOATS (WS_PART + (size_t)NTILE * KC)

typedef __attribute__((ext_vector_type(8))) short short8;
typedef __attribute__((ext_vector_type(4))) float f32x4;

__device__ __forceinline__ void split8(const float4 a, const float4 b,
                                       short8& h, short8& l) {
    const float f[8] = {a.x, a.y, a.z, a.w, b.x, b.y, b.z, b.w};
#pragma unroll
    for (int j = 0; j < 8; ++j) {
        const unsigned u  = __float_as_uint(f[j]);
        const unsigned hi = u & 0xffff0000u;
        const float lo    = f[j] - __uint_as_float(hi);
        h[j] = (short)(hi >> 16);
        l[j] = (short)(__float_as_uint(lo) >> 16);
    }
}

// ---------------------------------------------------------------------------
// k1: 124 blocks x 1024 threads; block handles tiles t1=bx and t2=bx+124.
// R11 theory: k1 was dispatch-ramp-bound (~0.1us/WG x 248). Halve the grid,
// double per-block work:
//  - BOTH tiles' x staged up-front (16 global loads in flight, one pass,
//    planes A+B in LDS: 152.7 KB total).
//  - tile2's cen ks=0 prefetch reloaded during tile1's bias/softmax.
//  - per-tile phases 1-3 identical to R10 (planes, in-reg softmax).
// ---------------------------------------------------------------------------
__global__ __launch_bounds__(1024, 4) void k1_main(
    const float* __restrict__ x, const float* __restrict__ cen,
    float* __restrict__ sa_out, float* __restrict__ outC,
    float* __restrict__ outS, int mode)
{
    __shared__ __align__(16) unsigned short xhA [64 * 128];
    __shared__ __align__(16) unsigned short xlA [64 * 128];
    __shared__ __align__(16) unsigned short xchA[128 * 64];
    __shared__ __align__(16) unsigned short xclA[128 * 64];
    __shared__ __align__(16) unsigned short xhB [64 * 128];
    __shared__ __align__(16) unsigned short xlB [64 * 128];
    __shared__ __align__(16) unsigned short xchB[128 * 64];
    __shared__ __align__(16) unsigned short xclB[128 * 64];
    __shared__ __align__(16) unsigned short wah [64 * 64];
    __shared__ __align__(16) unsigned short wal [64 * 64];
    __shared__ float2 ap[16 * 66];

    const int tid  = threadIdx.x;
    const int lane = tid & 63;
    const int wid  = tid >> 6;           // 0..15
    const int quad = lane >> 4;
    const int l15  = lane & 15;
    const int t1   = blockIdx.x;         // tile 1
    const int t2   = blockIdx.x + NBLK;  // tile 2

    // ---- cen row mapping for this wave's two m'-tiles (tile-independent) ----
    int wrow[2]; bool wvalid[2];
#pragma unroll
    for (int i = 0; i < 2; ++i) {
        const int mp = (2 * wid + i) * 16 + l15;   // padded m' = 8k+s
        const int s  = mp & 7;
        wvalid[i] = (s < 5);
        wrow[i]   = 5 * (mp >> 3) + s;
    }

    // ---- early prefetch: cen ks=0 (refreshed for tile2 inside do_tile) ----
    float4 pv0i[2], pv1i[2];
#pragma unroll
    for (int i = 0; i < 2; ++i) {
        pv0i[i] = make_float4(0.f, 0.f, 0.f, 0.f);
        pv1i[i] = pv0i[i];
        if (wvalid[i]) {
            const float* wp = cen + (size_t)wrow[i] * CC + quad * 8;
            pv0i[i] = *(const float4*)wp;
            pv1i[i] = *(const float4*)(wp + 4);
        }
    }

    // ---- phase 0: stage BOTH tiles (loads issued together) ----
    {
        const int pl = tid & 63;            // p within tile
        const int c0 = (tid >> 6) * 8;      // channel octet
        const int n1 = t1 / NPT, p01 = (t1 - n1 * NPT) * PT;
        const int n2 = t2 / NPT, p02 = (t2 - n2 * NPT) * PT;
        const bool pv1v = (p01 + pl) < PP;
        const bool pv2v = (p02 + pl) < PP;
        const float* s1 = x + (size_t)n1 * CC * PP + p01 + pl;
        const float* s2 = x + (size_t)n2 * CC * PP + p02 + pl;
        float v1[8], v2[8];
#pragma unroll
        for (int i = 0; i < 8; ++i) v1[i] = pv1v ? s1[(size_t)(c0 + i) * PP] : 0.f;
#pragma unroll
        for (int i = 0; i < 8; ++i) v2[i] = pv2v ? s2[(size_t)(c0 + i) * PP] : 0.f;

        auto emit = [&](const float* v, unsigned short* xh_, unsigned short* xl_,
                        unsigned short* xch_, unsigned short* xcl_) {
            unsigned short hv[8], lv[8];
#pragma unroll
            for (int i = 0; i < 8; ++i) {
                const unsigned u  = __float_as_uint(v[i]);
                const unsigned hi = u & 0xffff0000u;
                hv[i] = (unsigned short)(hi >> 16);
                lv[i] = (unsigned short)(__float_as_uint(v[i] - __uint_as_float(hi)) >> 16);
            }
            short8 H8, L8;
#pragma unroll
            for (int i = 0; i < 8; ++i) { H8[i] = (short)hv[i]; L8[i] = (short)lv[i]; }
            const int sx = (pl * 128 + c0) ^ ((pl & 7) << 3);
            *(short8*)&xh_[sx] = H8;
            *(short8*)&xl_[sx] = L8;
#pragma unroll
            for (int i = 0; i < 8; ++i) {
                const int ci  = c0 + i;
                const int sc2 = (ci * 64 + pl) ^ ((ci & 7) << 3);
                xch_[sc2] = hv[i];
                xcl_[sc2] = lv[i];
            }
        };
        emit(v1, xhA, xlA, xchA, xclA);
        emit(v2, xhB, xlB, xchB, xclB);
    }
    __syncthreads();

    // ---- per-tile phases 1-3 (R10 body, plane pointers parameterized) ----
    auto do_tile = [&](const int t,
                       const unsigned short* xh_, const unsigned short* xl_,
                       const unsigned short* xch_, const unsigned short* xcl_) {
        const int n  = t / NPT;
        const int p0 = (t - n * NPT) * PT;

        f32x4 dacc[4][2];
#pragma unroll
        for (int a = 0; a < 4; ++a) {
            dacc[a][0] = (f32x4){0.f, 0.f, 0.f, 0.f};
            dacc[a][1] = (f32x4){0.f, 0.f, 0.f, 0.f};
        }
        float ssq[2] = {0.f, 0.f};
        float4 pv0[2], pv1[2];
#pragma unroll
        for (int i = 0; i < 2; ++i) { pv0[i] = pv0i[i]; pv1[i] = pv1i[i]; }

#pragma unroll 1
        for (int ks = 0; ks < 4; ++ks) {
            short8 ch[2], cl[2];
#pragma unroll
            for (int i = 0; i < 2; ++i) {
                const float4 a4 = pv0[i], b4 = pv1[i];
                ssq[i] += a4.x * a4.x + a4.y * a4.y + a4.z * a4.z + a4.w * a4.w
                        + b4.x * b4.x + b4.y * b4.y + b4.z * b4.z + b4.w * b4.w;
                split8(a4, b4, ch[i], cl[i]);
            }
            if (ks < 3) {
#pragma unroll
                for (int i = 0; i < 2; ++i) {
                    pv0[i] = make_float4(0.f, 0.f, 0.f, 0.f);
                    pv1[i] = pv0[i];
                    if (wvalid[i]) {
                        const float* wp = cen + (size_t)wrow[i] * CC + (ks + 1) * 32 + quad * 8;
                        pv0[i] = *(const float4*)wp;
                        pv1[i] = *(const float4*)(wp + 4);
                    }
                }
            }
#pragma unroll
            for (int a = 0; a < 4; ++a) {
                const int arow = a * 16 + l15;
                const int sidx = (arow * 128 + ks * 32 + quad * 8) ^ ((arow & 7) << 3);
                const short8 xh8 = *(const short8*)&xh_[sidx];
                const short8 xl8 = *(const short8*)&xl_[sidx];
#pragma unroll
                for (int i = 0; i < 2; ++i) {
                    dacc[a][i] = __builtin_amdgcn_mfma_f32_16x16x32_bf16(ch[i], xh8, dacc[a][i], 0, 0, 0);
                    dacc[a][i] = __builtin_amdgcn_mfma_f32_16x16x32_bf16(ch[i], xl8, dacc[a][i], 0, 0, 0);
                    dacc[a][i] = __builtin_amdgcn_mfma_f32_16x16x32_bf16(cl[i], xh8, dacc[a][i], 0, 0, 0);
                }
            }
        }

        // refresh ks=0 prefetch for the NEXT tile (hidden under softmax)
#pragma unroll
        for (int i = 0; i < 2; ++i) {
            if (wvalid[i]) {
                const float* wp = cen + (size_t)wrow[i] * CC + quad * 8;
                pv0i[i] = *(const float4*)wp;
                pv1i[i] = *(const float4*)(wp + 4);
            }
        }

        // bias from ssq
        float bvr[2][4];
#pragma unroll
        for (int i = 0; i < 2; ++i) {
            float ss = ssq[i];
            ss += __shfl_xor(ss, 16);
            ss += __shfl_xor(ss, 32);
            const float bl = ((l15 & 7) < 5) ? (-ALPHAF * sqrtf(ss)) : -3.0e38f;
#pragma unroll
            for (int r = 0; r < 4; ++r)
                bvr[i][r] = __shfl(bl, quad * 4 + r);
        }
#pragma unroll
        for (int i = 0; i < 2; ++i)
#pragma unroll
            for (int a = 0; a < 4; ++a)
#pragma unroll
                for (int r = 0; r < 4; ++r)
                    dacc[a][i][r] = 2.f * ALPHAF * dacc[a][i][r] + bvr[i][r];

        // alpha partials
#pragma unroll
        for (int a = 0; a < 4; ++a) {
            const float l0 = dacc[a][0][0];
            const float l1 = dacc[a][1][0];
            const float m2 = fmaxf(l0, l1);
            const float mo = __shfl_xor(m2, 32);
            const float m4 = fmaxf(m2, mo);
            float se = __expf(l0 - m4) + __expf(l1 - m4);
            se += __shfl_xor(se, 32);
            if ((lane & 48) == 0) ap[wid * 66 + a * 16 + l15] = make_float2(m4, se);
        }
        __syncthreads();

        // alpha finalize + in-register beta softmax
        float gmv, arv;
        {
            float gm = -3.0e38f;
#pragma unroll
            for (int w = 0; w < 16; ++w) gm = fmaxf(gm, ap[w * 66 + lane].x);
            float s = 0.f;
#pragma unroll
            for (int w = 0; w < 16; ++w) {
                const float2 v = ap[w * 66 + lane];
                s += v.y * __expf(v.x - gm);
            }
            gmv = gm; arv = 1.0f / s;
        }

        const int  kb  = 4 * wid + ((lane >> 5) & 1);
        const bool evq = ((lane & 16) == 0);
        float psum2[2] = {0.f, 0.f};
#pragma unroll
        for (int a = 0; a < 4; ++a) {
            const int p = a * 16 + l15;
            const float gm_p = __shfl(gmv, p);
            const float ar_p = __shfl(arv, p);
            const bool pvalid = (p0 + p) < PP;
#pragma unroll
            for (int i = 0; i < 2; ++i) {
                const f32x4 lg = dacc[a][i];
                const float s4 = __shfl_xor(lg[0], 16);
                float m5 = fmaxf(fmaxf(lg[0], lg[1]), fmaxf(lg[2], lg[3]));
                m5 = fmaxf(m5, s4);
                const float e0 = __expf(lg[0] - m5);
                const float d5 = e0 + __expf(lg[1] - m5) + __expf(lg[2] - m5)
                               + __expf(lg[3] - m5) + __expf(s4 - m5);
                const float sa = __expf(lg[0] - gm_p) * ar_p * (e0 / d5);
                const float wa = pvalid ? (1.0f + sa) : 0.0f;
                if (evq) {
                    const int kk = kb + 2 * i;
                    const int si = (kk * 64 + p) ^ ((kk & 7) << 3);
                    const unsigned u  = __float_as_uint(wa);
                    const unsigned hi = u & 0xffff0000u;
                    wah[si] = (unsigned short)(hi >> 16);
                    wal[si] = (unsigned short)(__float_as_uint(wa - __uint_as_float(hi)) >> 16);
                }
                psum2[i] += wa;
            }
        }
#pragma unroll
        for (int i = 0; i < 2; ++i) {
            float s = psum2[i];
            s += __shfl_xor(s, 1);
            s += __shfl_xor(s, 2);
            s += __shfl_xor(s, 4);
            s += __shfl_xor(s, 8);
            if ((lane & 31) == 0) {
                const int k = kb + 2 * i;
                if (mode == 0) outS[(size_t)t * KC + k] = s;
                else           atomicAdd(&outS[(size_t)n * KC + k], s);
            }
        }
        __syncthreads();

        // sa tail (drain overlaps phase 3)
        {
            float* san = sa_out + (size_t)n * KC * PP;
            const int k  = tid >> 4;
            const int p4 = (tid & 15) * 4;
            const int pg = p0 + p4;
            if (pg < PP) {
                const int si = (k * 64 + p4) ^ ((k & 7) << 3);
                const uint2 qh = *(const uint2*)&wah[si];
                const uint2 ql = *(const uint2*)&wal[si];
                const unsigned hh[2] = {qh.x, qh.y};
                const unsigned ll[2] = {ql.x, ql.y};
                float4 sv; float* svp = &sv.x;
#pragma unroll
                for (int j = 0; j < 4; ++j) {
                    const unsigned h16 = (hh[j >> 1] >> ((j & 1) * 16)) & 0xffffu;
                    const unsigned l16 = (ll[j >> 1] >> ((j & 1) * 16)) & 0xffffu;
                    const float wa = __uint_as_float(h16 << 16) + __uint_as_float(l16 << 16);
                    svp[j] = wa - 1.0f;
                }
                *(float4*)&san[(size_t)k * PP + pg] = sv;
            }
        }

        // phase 3: stage-C MFMA
        const int kt  = wid & 3;
        const int ct0 = (wid >> 2) * 2;
        f32x4 cacc[2];
        cacc[0] = (f32x4){0.f, 0.f, 0.f, 0.f};
        cacc[1] = (f32x4){0.f, 0.f, 0.f, 0.f};
#pragma unroll
        for (int ks = 0; ks < 64; ks += 32) {
            const int arow = kt * 16 + l15;
            const int sa_  = (arow * 64 + ks + quad * 8) ^ ((arow & 7) << 3);
            const short8 ah = *(const short8*)&wah[sa_];
            const short8 al = *(const short8*)&wal[sa_];
#pragma unroll
            for (int tt = 0; tt < 2; ++tt) {
                const int crow = (ct0 + tt) * 16 + l15;
                const int sb   = (crow * 64 + ks + quad * 8) ^ ((crow & 7) << 3);
                const short8 bh = *(const short8*)&xch_[sb];
                const short8 bl = *(const short8*)&xcl_[sb];
                cacc[tt] = __builtin_amdgcn_mfma_f32_16x16x32_bf16(ah, bh, cacc[tt], 0, 0, 0);
                cacc[tt] = __builtin_amdgcn_mfma_f32_16x16x32_bf16(ah, bl, cacc[tt], 0, 0, 0);
                cacc[tt] = __builtin_amdgcn_mfma_f32_16x16x32_bf16(al, bh, cacc[tt], 0, 0, 0);
            }
        }
        if (mode == 0) {
            float* dst = outC + (size_t)t * KC * CC;
#pragma unroll
            for (int tt = 0; tt < 2; ++tt) {
                const int c = (ct0 + tt) * 16 + l15;
#pragma unroll
                for (int r = 0; r < 4; ++r)
                    dst[(kt * 16 + 4 * quad + r) * CC + c] = cacc[tt][r];
            }
        } else {
            float* dst = outC + (size_t)n * KC * CC;
#pragma unroll
            for (int tt = 0; tt < 2; ++tt) {
                const int c = (ct0 + tt) * 16 + l15;
#pragma unroll
                for (int r = 0; r < 4; ++r)
                    atomicAdd(&dst[(kt * 16 + 4 * quad + r) * CC + c], cacc[tt][r]);
            }
        }
    };

    do_tile(t1, xhA, xlA, xchA, xclA);
    __syncthreads();   // protect ap / wah / wal reuse across tiles
    do_tile(t2, xhB, xlB, xchB, xclB);
}

// ---------------------------------------------------------------------------
// k2 (slab mode): reduce 31 partial slabs, subtract rep*Swa, normalize, /8
// (R9 indexing: slab t = n*NPT + pt)
// ---------------------------------------------------------------------------
__global__ __launch_bounds__(128) void k2_slab(
    const float* __restrict__ part, const float* __restrict__ ps,
    const float* __restrict__ cen, float* __restrict__ flat)
{
    __shared__ float w2[2];
    const int b = blockIdx.x;        // n*64 + k
    const int n = b >> 6;
    const int k = b & 63;
    const int c = threadIdx.x;       // 0..127
    const float* pb = part + (size_t)n * NPT * KC * CC + (size_t)k * CC + c;
    float v = 0.f;
#pragma unroll 8
    for (int pt = 0; pt < NPT; ++pt) v += pb[(size_t)pt * KC * CC];
    const float* psb = ps + (size_t)n * NPT * KC + k;
    float sw = 0.f;
#pragma unroll
    for (int pt = 0; pt < NPT; ++pt) sw += psb[(size_t)pt * KC];
    v -= cen[(size_t)k * S1C * CC + c] * sw;

    float ss = v * v;
#pragma unroll
    for (int off = 32; off > 0; off >>= 1) ss += __shfl_down(ss, off);
    if ((c & 63) == 0) w2[c >> 6] = ss;
    __syncthreads();
    const float norm = sqrtf(w2[0] + w2[1]);
    const float scale = 1.0f / (fmaxf(norm, EPSF) * 8.0f);
    flat[(size_t)b * CC + c] = v * scale;
}

// ---------------------------------------------------------------------------
// k2 (fallback/atomic mode)
// ---------------------------------------------------------------------------
__global__ __launch_bounds__(128) void k2_final(
    const float* __restrict__ accC, const float* __restrict__ accS,
    const float* __restrict__ cen, float* __restrict__ flat)
{
    __shared__ float w2[2];
    const int b = blockIdx.x;
    const int k = b & 63;
    const int c = threadIdx.x;
    const float v = accC[(size_t)b * CC + c] -
                    cen[(size_t)k * S1C * CC + c] * accS[b];
    float ss = v * v;
#pragma unroll
    for (int off = 32; off > 0; off >>= 1) ss += __shfl_down(ss, off);
    if ((c & 63) == 0) w2[c >> 6] = ss;
    __syncthreads();
    const float norm = sqrtf(w2[0] + w2[1]);
    const float scale = 1.0f / (fmaxf(norm, EPSF) * 8.0f);
    flat[(size_t)b * CC + c] = v * scale;
}

// ---------------------------------------------------------------------------
extern "C" void kernel_launch(void* const* d_in, const int* in_sizes, int n_in,
                              void* d_out, int out_size, void* d_ws, size_t ws_size,
                              hipStream_t stream) {
    const float* x   = (const float*)d_in[0];   // [8][128][44][44]
    const float* cen = (const float*)d_in[1];   // [64][5][128]
    float* out  = (float*)d_out;
    float* flat = out;                           // [8][8192]
    float* sa   = out + (size_t)NB * KC * CC;    // [8][64][1][1936]
    float* ws   = (float*)d_ws;

    if (ws_size >= WS_MAIN_FLOATS * 4) {
        float* part = ws;
        float* ps   = part + WS_PART;
        k1_main<<<NBLK, 1024, 0, stream>>>(x, cen, sa, part, ps, 0);
        k2_slab<<<NB * KC, 128, 0, stream>>>(part, ps, cen, flat);
    } else {
        float* accC = ws;
        float* accS = accC + (size_t)NB * KC * CC;
        hipMemsetAsync(accC, 0, (size_t)(NB * KC * CC + NB * KC) * 4, stream);
        k1_main<<<NBLK, 1024, 0, stream>>>(x, cen, sa, accC, accS, 1);
        k2_final<<<NB * KC, 128, 0, stream>>>(accC, accS, cen, flat);
    }
}

// Round 12
// 79.684 us; speedup vs baseline: 1.1523x; 1.1523x over previous
//
#include <hip/hip_runtime.h>
#include <math.h>

#define NB 8
#define KC 64
#define S1C 5
#define CC 128
#define PP 1936
#define PT 64
#define NPT 31             /* ceil(1936/64) */
#define NTILE (NB * NPT)   /* 248 */
#define ALPHAF 1500.0f
#define EPSF 1e-12f

/* ws layout (floats): part[248][64][128] ; ps[248][64]  (~8.2 MB)
   slab index bx = pt*8 + n  (XCD co-location: all blocks of batch n on
   XCD n under round-robin bx%8 assignment; part[n] ~1MB fits 4MiB L2) */
#define WS_PART  ((size_t)NTILE * KC * CC)
#define WS_MAIN_FLOATS (WS_PART + (size_t)NTILE * KC)

typedef __attribute__((ext_vector_type(8))) short short8;
typedef __attribute__((ext_vector_type(4))) float f32x4;

__device__ __forceinline__ void split8(const float4 a, const float4 b,
                                       short8& h, short8& l) {
    const float f[8] = {a.x, a.y, a.z, a.w, b.x, b.y, b.z, b.w};
#pragma unroll
    for (int j = 0; j < 8; ++j) {
        const unsigned u  = __float_as_uint(f[j]);
        const unsigned hi = u & 0xffff0000u;
        const float lo    = f[j] - __uint_as_float(hi);
        h[j] = (short)(hi >> 16);
        l[j] = (short)(__float_as_uint(lo) >> 16);
    }
}

// ---------------------------------------------------------------------------
// k1: per (n, p-tile of 64), 1024 threads = 16 waves, 3 barriers.
// Final converged structure (best measured: 80.1 us):
//  - XCD co-location: n = bx&7, pt = bx>>3.
//  - bf16 hi/lo LDS planes, XOR-swizzled; ds_read_b128 IS the MFMA operand.
//  - cen loaded directly (read-only, L3-clean), software-pipelined; bias
//    computed inline from the same loads (ssq + quad-reduce).
//  - swapped MFMA operands put the s-dim in accumulator regs -> in-register
//    5-term beta softmax, one shfl per (a,i); alpha via 2-shfl partials.
//  - sa tail from wah/wal planes, coalesced, hoisted before phase 3.
// ---------------------------------------------------------------------------
__global__ __launch_bounds__(1024, 4) void k1_main(
    const float* __restrict__ x, const float* __restrict__ cen,
    float* __restrict__ sa_out, float* __restrict__ outC,
    float* __restrict__ outS, int mode)
{
    __shared__ __align__(16) unsigned short xh [64 * 128];  // 16 KB x^T hi
    __shared__ __align__(16) unsigned short xl [64 * 128];  // 16 KB x^T lo
    __shared__ __align__(16) unsigned short xch[128 * 64];  // 16 KB x  hi
    __shared__ __align__(16) unsigned short xcl[128 * 64];  // 16 KB x  lo
    __shared__ __align__(16) unsigned short wah[64 * 64];   //  8 KB wa hi
    __shared__ __align__(16) unsigned short wal[64 * 64];   //  8 KB wa lo
    __shared__ float2 ap[16 * 66];                          // alpha partials

    const int tid  = threadIdx.x;
    const int lane = tid & 63;
    const int wid  = tid >> 6;           // 0..15
    const int quad = lane >> 4;
    const int l15  = lane & 15;
    const int bx   = blockIdx.x;
    const int n    = bx & 7;             // XCD co-location decode
    const int pt   = bx >> 3;
    const int p0   = pt * PT;

    // ---- cen row mapping for this wave's two m'-tiles ----
    int wrow[2]; bool wvalid[2];
#pragma unroll
    for (int i = 0; i < 2; ++i) {
        const int mp = (2 * wid + i) * 16 + l15;   // padded m' = 8k+s
        const int s  = mp & 7;
        wvalid[i] = (s < 5);
        wrow[i]   = 5 * (mp >> 3) + s;
    }

    // ---- prefetch ks=0 cen float4s (read-only input, L3-clean) ----
    float4 pv0[2], pv1[2];
#pragma unroll
    for (int i = 0; i < 2; ++i) {
        pv0[i] = make_float4(0.f, 0.f, 0.f, 0.f);
        pv1[i] = pv0[i];
        if (wvalid[i]) {
            const float* wp = cen + (size_t)wrow[i] * CC + quad * 8;
            pv0[i] = *(const float4*)wp;
            pv1[i] = *(const float4*)(wp + 4);
        }
    }

    // ---- phase 0: load x (coalesced), split, write all four planes ----
    const float* xn = x + (size_t)n * CC * PP;
    {
        const int pl = tid & 63;            // p within tile
        const int c0 = (tid >> 6) * 8;      // channel octet
        const bool pv = (p0 + pl) < PP;
        const float* src = xn + p0 + pl;
        float v[8];
#pragma unroll
        for (int i = 0; i < 8; ++i)
            v[i] = pv ? src[(size_t)(c0 + i) * PP] : 0.f;
        unsigned short hv[8], lv[8];
#pragma unroll
        for (int i = 0; i < 8; ++i) {
            const unsigned u  = __float_as_uint(v[i]);
            const unsigned hi = u & 0xffff0000u;
            hv[i] = (unsigned short)(hi >> 16);
            lv[i] = (unsigned short)(__float_as_uint(v[i] - __uint_as_float(hi)) >> 16);
        }
        short8 H8, L8;
#pragma unroll
        for (int i = 0; i < 8; ++i) { H8[i] = (short)hv[i]; L8[i] = (short)lv[i]; }
        const int sx = (pl * 128 + c0) ^ ((pl & 7) << 3);
        *(short8*)&xh[sx] = H8;
        *(short8*)&xl[sx] = L8;
#pragma unroll
        for (int i = 0; i < 8; ++i) {
            const int ci  = c0 + i;
            const int sc2 = (ci * 64 + pl) ^ ((ci & 7) << 3);
            xch[sc2] = hv[i];
            xcl[sc2] = lv[i];
        }
    }
    __syncthreads();

    // ---- phase 1: logits MFMA (A = cen direct, B = x^T planes) ----
    // D[m'][p]: lane holds col p = a*16 + l15; rows m'off = quad*4 + r.
    f32x4 dacc[4][2];
#pragma unroll
    for (int a = 0; a < 4; ++a) {
        dacc[a][0] = (f32x4){0.f, 0.f, 0.f, 0.f};
        dacc[a][1] = (f32x4){0.f, 0.f, 0.f, 0.f};
    }
    float ssq[2] = {0.f, 0.f};

#pragma unroll 1
    for (int ks = 0; ks < 4; ++ks) {
        // split current ks fragments + accumulate row-norm partials
        short8 ch[2], cl[2];
#pragma unroll
        for (int i = 0; i < 2; ++i) {
            const float4 a4 = pv0[i], b4 = pv1[i];
            ssq[i] += a4.x * a4.x + a4.y * a4.y + a4.z * a4.z + a4.w * a4.w
                    + b4.x * b4.x + b4.y * b4.y + b4.z * b4.z + b4.w * b4.w;
            split8(a4, b4, ch[i], cl[i]);
        }
        // prefetch next ks (hidden under the MFMAs below)
        if (ks < 3) {
#pragma unroll
            for (int i = 0; i < 2; ++i) {
                pv0[i] = make_float4(0.f, 0.f, 0.f, 0.f);
                pv1[i] = pv0[i];
                if (wvalid[i]) {
                    const float* wp = cen + (size_t)wrow[i] * CC + (ks + 1) * 32 + quad * 8;
                    pv0[i] = *(const float4*)wp;
                    pv1[i] = *(const float4*)(wp + 4);
                }
            }
        }
#pragma unroll
        for (int a = 0; a < 4; ++a) {
            const int arow = a * 16 + l15;
            const int sidx = (arow * 128 + ks * 32 + quad * 8) ^ ((arow & 7) << 3);
            const short8 xh8 = *(const short8*)&xh[sidx];
            const short8 xl8 = *(const short8*)&xl[sidx];
#pragma unroll
            for (int i = 0; i < 2; ++i) {
                dacc[a][i] = __builtin_amdgcn_mfma_f32_16x16x32_bf16(ch[i], xh8, dacc[a][i], 0, 0, 0);
                dacc[a][i] = __builtin_amdgcn_mfma_f32_16x16x32_bf16(ch[i], xl8, dacc[a][i], 0, 0, 0);
                dacc[a][i] = __builtin_amdgcn_mfma_f32_16x16x32_bf16(cl[i], xh8, dacc[a][i], 0, 0, 0);
            }
        }
    }

    // ---- bias from ssq: quad-reduce + redistribute ----
    float bvr[2][4];
#pragma unroll
    for (int i = 0; i < 2; ++i) {
        float ss = ssq[i];
        ss += __shfl_xor(ss, 16);
        ss += __shfl_xor(ss, 32);
        const float bl = ((l15 & 7) < 5) ? (-ALPHAF * sqrtf(ss)) : -3.0e38f;
#pragma unroll
        for (int r = 0; r < 4; ++r)
            bvr[i][r] = __shfl(bl, quad * 4 + r);
    }

    // lg = 2*ALPHA*dot + bias[m'], m' = (2wid+i)*16 + quad*4 + r
#pragma unroll
    for (int i = 0; i < 2; ++i)
#pragma unroll
        for (int a = 0; a < 4; ++a)
#pragma unroll
            for (int r = 0; r < 4; ++r)
                dacc[a][i][r] = 2.f * ALPHAF * dacc[a][i][r] + bvr[i][r];

    // alpha partials (s=0 at reg0 of even quads; pair via shfl_xor 32)
#pragma unroll
    for (int a = 0; a < 4; ++a) {
        const float l0 = dacc[a][0][0];
        const float l1 = dacc[a][1][0];
        const float m2 = fmaxf(l0, l1);
        const float mo = __shfl_xor(m2, 32);
        const float m4 = fmaxf(m2, mo);
        float se = __expf(l0 - m4) + __expf(l1 - m4);
        se += __shfl_xor(se, 32);
        if ((lane & 48) == 0) ap[wid * 66 + a * 16 + l15] = make_float2(m4, se);
    }
    __syncthreads();

    // ---- phase 2: alpha finalize + in-register beta softmax ----
    float gmv, arv;
    {
        float gm = -3.0e38f;
#pragma unroll
        for (int w = 0; w < 16; ++w) gm = fmaxf(gm, ap[w * 66 + lane].x);
        float s = 0.f;
#pragma unroll
        for (int w = 0; w < 16; ++w) {
            const float2 v = ap[w * 66 + lane];
            s += v.y * __expf(v.x - gm);
        }
        gmv = gm; arv = 1.0f / s;
    }

    const int  kb  = 4 * wid + ((lane >> 5) & 1);   // even-quad k = kb + 2i
    const bool evq = ((lane & 16) == 0);
    float psum2[2] = {0.f, 0.f};
#pragma unroll
    for (int a = 0; a < 4; ++a) {
        const int p = a * 16 + l15;
        const float gm_p = __shfl(gmv, p);
        const float ar_p = __shfl(arv, p);
        const bool pvalid = (p0 + p) < PP;
#pragma unroll
        for (int i = 0; i < 2; ++i) {
            const f32x4 lg = dacc[a][i];
            const float s4 = __shfl_xor(lg[0], 16);  // partner quad's s=4 logit
            float m5 = fmaxf(fmaxf(lg[0], lg[1]), fmaxf(lg[2], lg[3]));
            m5 = fmaxf(m5, s4);
            const float e0 = __expf(lg[0] - m5);
            const float d5 = e0 + __expf(lg[1] - m5) + __expf(lg[2] - m5)
                           + __expf(lg[3] - m5) + __expf(s4 - m5);
            const float sa = __expf(lg[0] - gm_p) * ar_p * (e0 / d5);
            const float wa = pvalid ? (1.0f + sa) : 0.0f;
            if (evq) {
                const int kk = kb + 2 * i;
                const int si = (kk * 64 + p) ^ ((kk & 7) << 3);
                const unsigned u  = __float_as_uint(wa);
                const unsigned hi = u & 0xffff0000u;
                wah[si] = (unsigned short)(hi >> 16);
                wal[si] = (unsigned short)(__float_as_uint(wa - __uint_as_float(hi)) >> 16);
            }
            psum2[i] += wa;
        }
    }
#pragma unroll
    for (int i = 0; i < 2; ++i) {
        float s = psum2[i];
        s += __shfl_xor(s, 1);
        s += __shfl_xor(s, 2);
        s += __shfl_xor(s, 4);
        s += __shfl_xor(s, 8);
        if ((lane & 31) == 0) {                      // l15==0 on even quads
            const int k = kb + 2 * i;
            if (mode == 0) outS[(size_t)bx * KC + k] = s;
            else           atomicAdd(&outS[(size_t)n * KC + k], s);
        }
    }
    __syncthreads();

    // ---- sa tail (hoisted): coalesced write, drain overlaps phase 3 ----
    {
        float* san = sa_out + (size_t)n * KC * PP;
        const int k  = tid >> 4;          // 0..63
        const int p4 = (tid & 15) * 4;    // 0..60
        const int pg = p0 + p4;
        if (pg < PP) {
            const int si = (k * 64 + p4) ^ ((k & 7) << 3);
            const uint2 qh = *(const uint2*)&wah[si];
            const uint2 ql = *(const uint2*)&wal[si];
            const unsigned hh[2] = {qh.x, qh.y};
            const unsigned ll[2] = {ql.x, ql.y};
            float4 sv; float* svp = &sv.x;
#pragma unroll
            for (int j = 0; j < 4; ++j) {
                const unsigned h16 = (hh[j >> 1] >> ((j & 1) * 16)) & 0xffffu;
                const unsigned l16 = (ll[j >> 1] >> ((j & 1) * 16)) & 0xffffu;
                const float wa = __uint_as_float(h16 << 16) + __uint_as_float(l16 << 16);
                svp[j] = wa - 1.0f;
            }
            *(float4*)&san[(size_t)k * PP + pg] = sv;
        }
    }

    // ---- phase 3: stage-C MFMA: C[k][c] = sum_p wa*x ----
    const int kt  = wid & 3;
    const int ct0 = (wid >> 2) * 2;
    f32x4 cacc[2];
    cacc[0] = (f32x4){0.f, 0.f, 0.f, 0.f};
    cacc[1] = (f32x4){0.f, 0.f, 0.f, 0.f};
#pragma unroll
    for (int ks = 0; ks < 64; ks += 32) {
        const int arow = kt * 16 + l15;
        const int sa_  = (arow * 64 + ks + quad * 8) ^ ((arow & 7) << 3);
        const short8 ah = *(const short8*)&wah[sa_];
        const short8 al = *(const short8*)&wal[sa_];
#pragma unroll
        for (int t = 0; t < 2; ++t) {
            const int crow = (ct0 + t) * 16 + l15;
            const int sb   = (crow * 64 + ks + quad * 8) ^ ((crow & 7) << 3);
            const short8 bh = *(const short8*)&xch[sb];
            const short8 bl = *(const short8*)&xcl[sb];
            cacc[t] = __builtin_amdgcn_mfma_f32_16x16x32_bf16(ah, bh, cacc[t], 0, 0, 0);
            cacc[t] = __builtin_amdgcn_mfma_f32_16x16x32_bf16(ah, bl, cacc[t], 0, 0, 0);
            cacc[t] = __builtin_amdgcn_mfma_f32_16x16x32_bf16(al, bh, cacc[t], 0, 0, 0);
        }
    }
    if (mode == 0) {
        float* dst = outC + (size_t)bx * KC * CC;
#pragma unroll
        for (int t = 0; t < 2; ++t) {
            const int c = (ct0 + t) * 16 + l15;
#pragma unroll
            for (int r = 0; r < 4; ++r)
                dst[(kt * 16 + 4 * quad + r) * CC + c] = cacc[t][r];
        }
    } else {
        float* dst = outC + (size_t)n * KC * CC;
#pragma unroll
        for (int t = 0; t < 2; ++t) {
            const int c = (ct0 + t) * 16 + l15;
#pragma unroll
            for (int r = 0; r < 4; ++r)
                atomicAdd(&dst[(kt * 16 + 4 * quad + r) * CC + c], cacc[t][r]);
        }
    }
}

// ---------------------------------------------------------------------------
// k2 (slab mode): reduce 31 partial slabs, subtract rep*Swa, normalize, /8.
// XCD co-location: n = b&7 -> reducer blocks of n land on XCD n, reading
// part[n]/ps[n] as LOCAL-L2 dirty hits (written by k1 blocks of n there).
// ---------------------------------------------------------------------------
__global__ __launch_bounds__(128) void k2_slab(
    const float* __restrict__ part, const float* __restrict__ ps,
    const float* __restrict__ cen, float* __restrict__ flat)
{
    __shared__ float w2[2];
    const int b = blockIdx.x;
    const int n = b & 7;             // co-located with k1 writers of n
    const int k = b >> 3;            // 0..63
    const int c = threadIdx.x;       // 0..127
    // slab bx = pt*8 + n  ->  base (n*KC + k), pt-stride 8*KC*CC
    const float* pb = part + ((size_t)n * KC + k) * CC + c;
    float v = 0.f;
#pragma unroll 8
    for (int pt = 0; pt < NPT; ++pt) v += pb[(size_t)pt * 8 * KC * CC];
    const float* psb = ps + (size_t)n * KC + k;
    float sw = 0.f;
#pragma unroll
    for (int pt = 0; pt < NPT; ++pt) sw += psb[(size_t)pt * 8 * KC];
    v -= cen[(size_t)k * S1C * CC + c] * sw;

    float ss = v * v;
#pragma unroll
    for (int off = 32; off > 0; off >>= 1) ss += __shfl_down(ss, off);
    if ((c & 63) == 0) w2[c >> 6] = ss;
    __syncthreads();
    const float norm = sqrtf(w2[0] + w2[1]);
    // flat-level norm is exactly sqrt(64)=8 (every row unit-norm, >> EPS)
    const float scale = 1.0f / (fmaxf(norm, EPSF) * 8.0f);
    flat[((size_t)n * KC + k) * CC + c] = v * scale;
}

// ---------------------------------------------------------------------------
// k2 (fallback/atomic mode)
// ---------------------------------------------------------------------------
__global__ __launch_bounds__(128) void k2_final(
    const float* __restrict__ accC, const float* __restrict__ accS,
    const float* __restrict__ cen, float* __restrict__ flat)
{
    __shared__ float w2[2];
    const int b = blockIdx.x;
    const int n = b & 7;
    const int k = b >> 3;
    const int c = threadIdx.x;
    const int slab = n * KC + k;
    const float v = accC[(size_t)slab * CC + c] -
                    cen[(size_t)k * S1C * CC + c] * accS[slab];
    float ss = v * v;
#pragma unroll
    for (int off = 32; off > 0; off >>= 1) ss += __shfl_down(ss, off);
    if ((c & 63) == 0) w2[c >> 6] = ss;
    __syncthreads();
    const float norm = sqrtf(w2[0] + w2[1]);
    const float scale = 1.0f / (fmaxf(norm, EPSF) * 8.0f);
    flat[(size_t)slab * CC + c] = v * scale;
}

// ---------------------------------------------------------------------------
extern "C" void kernel_launch(void* const* d_in, const int* in_sizes, int n_in,
                              void* d_out, int out_size, void* d_ws, size_t ws_size,
                              hipStream_t stream) {
    const float* x   = (const float*)d_in[0];   // [8][128][44][44]
    const float* cen = (const float*)d_in[1];   // [64][5][128]
    float* out  = (float*)d_out;
    float* flat = out;                           // [8][8192]
    float* sa   = out + (size_t)NB * KC * CC;    // [8][64][1][1936]
    float* ws   = (float*)d_ws;

    if (ws_size >= WS_MAIN_FLOATS * 4) {
        float* part = ws;
        float* ps   = part + WS_PART;
        k1_main<<<NTILE, 1024, 0, stream>>>(x, cen, sa, part, ps, 0);
        k2_slab<<<NB * KC, 128, 0, stream>>>(part, ps, cen, flat);
    } else {
        float* accC = ws;
        float* accS = accC + (size_t)NB * KC * CC;
        hipMemsetAsync(accC, 0, (size_t)(NB * KC * CC + NB * KC) * 4, stream);
        k1_main<<<NTILE, 1024, 0, stream>>>(x, cen, sa, accC, accS, 1);
        k2_final<<<NB * KC, 128, 0, stream>>>(accC, accS, cen, flat);
    }
}